// Round 1
// baseline (171.194 us; speedup 1.0000x reference)
//
#include <hip/hip_runtime.h>
#include <stdint.h>

#define BN_EPS 1e-3f

// ============================================================
// Weight prep:
//  - w1s[864]: sign floats, w1s[tap*32+c] = (w1<0 ? -1.f : 1.f)   (tap = (kh*3+kw)*3+ci)
//  - w2p/w3p/w4p: bit-packed signs, bit=1 <=> w<0, layout [(tap*CINW+wi)][COUT]
// ============================================================
template <int CIN, int COUT>
__device__ inline void packw(const float* __restrict__ w, uint32_t* __restrict__ wp, int idx) {
    const int CINW = CIN / 32;
    int co = idx % COUT;
    int t2 = idx / COUT;
    int wi = t2 % CINW;
    int tap = t2 / CINW;
    uint32_t word = 0;
#pragma unroll
    for (int bb = 0; bb < 32; bb++) {
        float val = w[((tap * CIN) + wi * 32 + bb) * COUT + co];
        word |= (uint32_t)(val < 0.f) << bb;
    }
    wp[idx] = word;
}

__global__ void pack_all(const float* __restrict__ w1, const float* __restrict__ w2,
                         const float* __restrict__ w3, const float* __restrict__ w4,
                         float* __restrict__ w1s, uint32_t* __restrict__ w2p,
                         uint32_t* __restrict__ w3p, uint32_t* __restrict__ w4p) {
    int idx = blockIdx.x * 256 + threadIdx.x;
    if (idx < 864) {
        // ste_sign: x >= 0 -> +1, x < 0 -> -1
        w1s[idx] = (w1[idx] < 0.f) ? -1.f : 1.f;
        return;
    }
    idx -= 864;
    if (idx < 576) { packw<32, 64>(w2, w2p, idx); return; }
    idx -= 576;
    if (idx < 2304) { packw<64, 128>(w3, w3p, idx); return; }
    idx -= 2304;
    if (idx < 9216) { packw<128, 256>(w4, w4p, idx); return; }
}

// ============================================================
// Layer 1: conv(x, sign(w1), VALID) + maxpool2 + bn + sign -> packed u32.
// Block 256 = 4 waves, tile 16x16 pooled pixels (wave = 16x4).
// __launch_bounds__(256,4): grid is exactly 4 blocks/CU, so allow up to
// 128 VGPRs -> full 4x12 window (48 regs) + acc[8][4] (32 regs) stay live.
// Sign weights come from a precomputed +-1.0f table read at wave-uniform
// addresses (scalarized to s_load) -> inner loop is 1 v_fmac per MAC with
// an SGPR multiplier, no per-MAC select, no LDS window re-reads.
// Tap accumulation order (kh,kw,ci) identical to previous version ->
// bit-identical y1p.
// ============================================================
__global__ __launch_bounds__(256, 4) void conv1_k(const float* __restrict__ x,
                                                  const float* __restrict__ w1s,
                                                  const float* __restrict__ m1,
                                                  const float* __restrict__ v1,
                                                  const float* __restrict__ b1,
                                                  uint32_t* __restrict__ y1p) {
    __shared__ __align__(16) float xt[34 * 104];   // 34 input rows x 102 col-floats (pad 104)

    int tile = blockIdx.x;
    int tx = tile & 3;
    int ty = (tile >> 2) & 3;
    int n  = tile >> 4;
    int ph0 = ty * 16, pw0 = tx * 16;
    int r0 = 2 * ph0;
    int cf0 = pw0 * 6;                 // col-float origin (x row = 384 floats)

    for (int i = threadIdx.x; i < 34 * 102; i += 256) {
        int r = i / 102, c = i % 102;
        int gr = r0 + r, gcf = cf0 + c;
        float vv = 0.f;
        if (gr < 128 && gcf < 384)
            vv = x[(size_t)(n * 128 + gr) * 384 + gcf];
        xt[r * 104 + c] = vv;
    }

    __syncthreads();

    int wave = threadIdx.x >> 6, lane = threadIdx.x & 63;
    int px = lane & 15, py = (wave << 2) + (lane >> 4);   // 0..15
    int ph = ph0 + py, pw = pw0 + px;

    // 4x4x3 input window in regs (float2 LDS reads, 8B aligned)
    float win[48];
#pragma unroll
    for (int r = 0; r < 4; r++) {
        const float2* bp = (const float2*)&xt[(2 * py + r) * 104 + 6 * px];
#pragma unroll
        for (int q = 0; q < 6; q++) {
            float2 f2 = bp[q];
            win[r * 12 + 2 * q]     = f2.x;
            win[r * 12 + 2 * q + 1] = f2.y;
        }
    }

    uint32_t word = 0;
#pragma unroll 1
    for (int cg = 0; cg < 4; cg++) {               // 8 channels per group
        float acc[8][4];
#pragma unroll
        for (int j = 0; j < 8; j++)
#pragma unroll
            for (int p = 0; p < 4; p++) acc[j][p] = 0.f;

        const float* sgc = w1s + cg * 8;           // wave-uniform base
#pragma unroll
        for (int kh = 0; kh < 3; kh++)
#pragma unroll
            for (int kw = 0; kw < 3; kw++)
#pragma unroll
                for (int ci = 0; ci < 3; ci++) {
                    int tap = (kh * 3 + kw) * 3 + ci;
                    float x00 = win[kh * 12 + kw * 3 + ci];
                    float x01 = win[kh * 12 + (kw + 1) * 3 + ci];
                    float x10 = win[(kh + 1) * 12 + kw * 3 + ci];
                    float x11 = win[(kh + 1) * 12 + (kw + 1) * 3 + ci];
                    // uniform address -> scalarized load, values land in SGPRs
                    float4 s0 = *(const float4*)(sgc + tap * 32);
                    float4 s1 = *(const float4*)(sgc + tap * 32 + 4);
                    float sv[8] = {s0.x, s0.y, s0.z, s0.w, s1.x, s1.y, s1.z, s1.w};
#pragma unroll
                    for (int j = 0; j < 8; j++) {
                        acc[j][0] += x00 * sv[j];
                        acc[j][1] += x01 * sv[j];
                        acc[j][2] += x10 * sv[j];
                        acc[j][3] += x11 * sv[j];
                    }
                }
#pragma unroll
        for (int j = 0; j < 8; j++) {
            float mx = fmaxf(fmaxf(acc[j][0], acc[j][1]), fmaxf(acc[j][2], acc[j][3]));
            int ch = cg * 8 + j;
            float y = (mx - m1[ch]) * rsqrtf(v1[ch] + BN_EPS) + b1[ch];
            word |= (uint32_t)(y < 0.f) << ch;
        }
    }

    if (ph < 63 && pw < 63)
        y1p[(n * 63 + ph) * 63 + pw] = word;
}

// ============================================================
// Layer 2: bconv(SAME, 63x63, CIN=32) + maxpool2 + bn + sign -> packed
// One wave per 4-pixel row group; lane = co. Window = 4x10 uniform words
// (SGPRs). Fast path for interior groups; only top/left edges need the
// generic path (right/bottom never pad: 63 odd, pool truncates).
// ============================================================
__global__ __launch_bounds__(256) void bconv2(const uint32_t* __restrict__ y1p,
                                              const uint32_t* __restrict__ w2p,
                                              const float* __restrict__ m,
                                              const float* __restrict__ v,
                                              const float* __restrict__ b,
                                              uint2* __restrict__ y2p) {
    int gw = __builtin_amdgcn_readfirstlane(blockIdx.x * 4 + (threadIdx.x >> 6));
    int lane = threadIdx.x & 63;
    int pwg = gw & 7;          // pixel group: pw = 4*pwg + p
    int t = gw >> 3;
    int ph = t % 31;
    int n = t / 31;

    uint32_t wq[9];
#pragma unroll
    for (int tap = 0; tap < 9; tap++) wq[tap] = w2p[tap * 64 + lane];
    float mm = m[lane], vv = v[lane], bb = b[lane];

    uint2 o0, o1, o2, o3;

    if (ph > 0 && pwg > 0) {
        int row0 = 2 * ph - 1, col0 = 8 * pwg - 1;
        uint32_t win[4][10];
#pragma unroll
        for (int r = 0; r < 4; r++)
#pragma unroll
            for (int c = 0; c < 10; c++)
                win[r][c] = y1p[(n * 63 + row0 + r) * 63 + min(col0 + c, 62)];

        uint2 res[4];
#pragma unroll
        for (int p = 0; p < 4; p++) {
            int a0 = 0, a1 = 0, a2 = 0, a3 = 0;
#pragma unroll
            for (int kh = 0; kh < 3; kh++)
#pragma unroll
                for (int kw = 0; kw < 3; kw++) {
                    uint32_t w = wq[kh * 3 + kw];
                    a0 += __popc(win[kh][2 * p + kw] ^ w);
                    a1 += __popc(win[kh][2 * p + kw + 1] ^ w);
                    a2 += __popc(win[kh + 1][2 * p + kw] ^ w);
                    a3 += __popc(win[kh + 1][2 * p + kw + 1] ^ w);
                }
            int mn = min(min(a0, a1), min(a2, a3));
            int best = 288 - 2 * mn;
            float y = ((float)best - mm) * rsqrtf(vv + BN_EPS) + bb;
            unsigned long long bal = __ballot(y < 0.f);
            res[p] = make_uint2((uint32_t)bal, (uint32_t)(bal >> 32));
        }
        o0 = res[0]; o1 = res[1]; o2 = res[2]; o3 = res[3];
    } else {
        uint2 res[4];
#pragma unroll
        for (int p = 0; p < 4; p++) {
            int pw = 4 * pwg + p;
            int best = -1000000;
            if (pw < 31) {
#pragma unroll
                for (int dy = 0; dy < 2; dy++)
#pragma unroll
                    for (int dx = 0; dx < 2; dx++) {
                        int oh = 2 * ph + dy, ow = 2 * pw + dx;
                        int acc = 0, K = 0;
                        for (int kh = 0; kh < 3; kh++) {
                            int ih = oh - 1 + kh;
                            if (ih < 0 || ih >= 63) continue;
                            for (int kw = 0; kw < 3; kw++) {
                                int iw = ow - 1 + kw;
                                if (iw < 0 || iw >= 63) continue;
                                acc += __popc(y1p[(n * 63 + ih) * 63 + iw] ^ wq[kh * 3 + kw]);
                                K += 32;
                            }
                        }
                        best = max(best, K - 2 * acc);
                    }
            }
            float y = ((float)best - mm) * rsqrtf(vv + BN_EPS) + bb;
            unsigned long long bal = __ballot(y < 0.f);
            res[p] = make_uint2((uint32_t)bal, (uint32_t)(bal >> 32));
        }
        o0 = res[0]; o1 = res[1]; o2 = res[2]; o3 = res[3];
    }

    uint2 rr = o0;
    if (lane == 1) rr = o1;
    if (lane == 2) rr = o2;
    if (lane == 3) rr = o3;
    int pws = 4 * pwg + lane;
    if (lane < 4 && pws < 31)
        y2p[(n * 31 + ph) * 31 + pws] = rr;
}

// ============================================================
// Layer 3: bconv(SAME, 31x31, CIN=64) + maxpool2 + bn + sign -> packed
// Wave per (2-pixel group, co-half). Window = 4x6 uint2 uniform words.
// ============================================================
__global__ __launch_bounds__(256) void bconv3(const uint2* __restrict__ y2p,
                                              const uint32_t* __restrict__ w3p,
                                              const float* __restrict__ m,
                                              const float* __restrict__ v,
                                              const float* __restrict__ b,
                                              uint32_t* __restrict__ y3p) {
    int gw = __builtin_amdgcn_readfirstlane(blockIdx.x * 4 + (threadIdx.x >> 6));
    int lane = threadIdx.x & 63;
    int half = gw & 1;
    int t = gw >> 1;
    int pwg = t & 7;           // pw = 2*pwg + p
    t >>= 3;
    int ph = t % 15;
    int n = t / 15;
    int co = half * 64 + lane;

    uint32_t wq0[9], wq1[9];
#pragma unroll
    for (int tap = 0; tap < 9; tap++) {
        wq0[tap] = w3p[(tap * 2 + 0) * 128 + co];
        wq1[tap] = w3p[(tap * 2 + 1) * 128 + co];
    }
    float mm = m[co], vv = v[co], bb = b[co];

    unsigned long long bal0, bal1;

    if (ph > 0 && pwg > 0) {
        int row0 = 2 * ph - 1, col0 = 4 * pwg - 1;
        uint2 win[4][6];
#pragma unroll
        for (int r = 0; r < 4; r++)
#pragma unroll
            for (int c = 0; c < 6; c++)
                win[r][c] = y2p[(n * 31 + row0 + r) * 31 + min(col0 + c, 30)];

        unsigned long long bals[2];
#pragma unroll
        for (int p = 0; p < 2; p++) {
            int a0 = 0, a1 = 0, a2 = 0, a3 = 0;
#pragma unroll
            for (int kh = 0; kh < 3; kh++)
#pragma unroll
                for (int kw = 0; kw < 3; kw++) {
                    int tap = kh * 3 + kw;
                    uint32_t u0 = wq0[tap], u1 = wq1[tap];
                    a0 += __popc(win[kh][2 * p + kw].x ^ u0) + __popc(win[kh][2 * p + kw].y ^ u1);
                    a1 += __popc(win[kh][2 * p + kw + 1].x ^ u0) + __popc(win[kh][2 * p + kw + 1].y ^ u1);
                    a2 += __popc(win[kh + 1][2 * p + kw].x ^ u0) + __popc(win[kh + 1][2 * p + kw].y ^ u1);
                    a3 += __popc(win[kh + 1][2 * p + kw + 1].x ^ u0) + __popc(win[kh + 1][2 * p + kw + 1].y ^ u1);
                }
            int mn = min(min(a0, a1), min(a2, a3));
            int best = 576 - 2 * mn;
            float y = ((float)best - mm) * rsqrtf(vv + BN_EPS) + bb;
            bals[p] = __ballot(y < 0.f);
        }
        bal0 = bals[0]; bal1 = bals[1];
    } else {
        unsigned long long bals[2];
#pragma unroll
        for (int p = 0; p < 2; p++) {
            int pw = 2 * pwg + p;
            int best = -1000000;
            if (pw < 15) {
#pragma unroll
                for (int dy = 0; dy < 2; dy++)
#pragma unroll
                    for (int dx = 0; dx < 2; dx++) {
                        int oh = 2 * ph + dy, ow = 2 * pw + dx;
                        int acc = 0, K = 0;
                        for (int kh = 0; kh < 3; kh++) {
                            int ih = oh - 1 + kh;
                            if (ih < 0 || ih >= 31) continue;
                            for (int kw = 0; kw < 3; kw++) {
                                int iw = ow - 1 + kw;
                                if (iw < 0 || iw >= 31) continue;
                                uint2 iv = y2p[(n * 31 + ih) * 31 + iw];
                                int tap = kh * 3 + kw;
                                acc += __popc(iv.x ^ wq0[tap]) + __popc(iv.y ^ wq1[tap]);
                                K += 64;
                            }
                        }
                        best = max(best, K - 2 * acc);
                    }
            }
            float y = ((float)best - mm) * rsqrtf(vv + BN_EPS) + bb;
            bals[p] = __ballot(y < 0.f);
        }
        bal0 = bals[0]; bal1 = bals[1];
    }

    // lane k in 0..3 stores word k: pixel = k>>1, wordhalf = k&1
    uint32_t val = (uint32_t)bal0;
    if (lane == 1) val = (uint32_t)(bal0 >> 32);
    if (lane == 2) val = (uint32_t)bal1;
    if (lane == 3) val = (uint32_t)(bal1 >> 32);
    int p = lane >> 1;
    int pw = 2 * pwg + p;
    if (lane < 4 && pw < 15) {
        int pixel = (n * 15 + ph) * 15 + pw;
        y3p[pixel * 4 + half * 2 + (lane & 1)] = val;
    }
}

// ============================================================
// Layer 4: bconv(SAME, 15x15, CIN=128) + maxpool2 + bn -> f32 out
// Block per pixel; wave = one co-quad (co = wave*64 + lane).
// ============================================================
__global__ __launch_bounds__(256) void bconv4(const uint4* __restrict__ y3p,
                                              const uint32_t* __restrict__ w4p,
                                              const float* __restrict__ m,
                                              const float* __restrict__ v,
                                              const float* __restrict__ b,
                                              float* __restrict__ out) {
    int pixel = blockIdx.x;
    int lane = threadIdx.x & 63;
    int co = (threadIdx.x >> 6) * 64 + lane;
    int pw = pixel % 7;
    int t = pixel / 7;
    int ph = t % 7;
    int n = t / 7;

    uint4 wq[9];
#pragma unroll
    for (int tap = 0; tap < 9; tap++) {
        wq[tap].x = w4p[(tap * 4 + 0) * 256 + co];
        wq[tap].y = w4p[(tap * 4 + 1) * 256 + co];
        wq[tap].z = w4p[(tap * 4 + 2) * 256 + co];
        wq[tap].w = w4p[(tap * 4 + 3) * 256 + co];
    }

    int best;
    if (ph > 0 && pw > 0) {
        const uint4* p = y3p + (n * 15 + (2 * ph - 1)) * 15 + (2 * pw - 1);
        int a0 = 0, a1 = 0, a2 = 0, a3 = 0;
#pragma unroll
        for (int r = 0; r < 4; r++)
#pragma unroll
            for (int c = 0; c < 4; c++) {
                uint4 iv = p[r * 15 + c];
#pragma unroll
                for (int kh = 0; kh < 3; kh++) {
                    int dy = r - kh;
                    if (dy < 0 || dy > 1) continue;
#pragma unroll
                    for (int kw = 0; kw < 3; kw++) {
                        int dx = c - kw;
                        if (dx < 0 || dx > 1) continue;
                        int tap = kh * 3 + kw;
                        int pc = __popc(iv.x ^ wq[tap].x) + __popc(iv.y ^ wq[tap].y)
                               + __popc(iv.z ^ wq[tap].z) + __popc(iv.w ^ wq[tap].w);
                        if (dy == 0 && dx == 0) a0 += pc;
                        else if (dy == 0) a1 += pc;
                        else if (dx == 0) a2 += pc;
                        else a3 += pc;
                    }
                }
            }
        best = max(max(1152 - 2 * a0, 1152 - 2 * a1), max(1152 - 2 * a2, 1152 - 2 * a3));
    } else {
        best = -1000000;
#pragma unroll
        for (int dy = 0; dy < 2; dy++)
#pragma unroll
            for (int dx = 0; dx < 2; dx++) {
                int oh = 2 * ph + dy, ow = 2 * pw + dx;
                int acc = 0, K = 0;
                for (int kh = 0; kh < 3; kh++) {
                    int ih = oh - 1 + kh;
                    if (ih < 0 || ih >= 15) continue;
                    for (int kw = 0; kw < 3; kw++) {
                        int iw = ow - 1 + kw;
                        if (iw < 0 || iw >= 15) continue;
                        uint4 iv = y3p[(n * 15 + ih) * 15 + iw];
                        int tap = kh * 3 + kw;
                        acc += __popc(iv.x ^ wq[tap].x) + __popc(iv.y ^ wq[tap].y)
                             + __popc(iv.z ^ wq[tap].z) + __popc(iv.w ^ wq[tap].w);
                        K += 128;
                    }
                }
                best = max(best, K - 2 * acc);
            }
    }
    float y = ((float)best - m[co]) * rsqrtf(v[co] + BN_EPS) + b[co];
    out[pixel * 256 + co] = y;
}

extern "C" void kernel_launch(void* const* d_in, const int* in_sizes, int n_in,
                              void* d_out, int out_size, void* d_ws, size_t ws_size,
                              hipStream_t stream) {
    const float* x  = (const float*)d_in[0];
    const float* w1 = (const float*)d_in[1];
    const float* m1 = (const float*)d_in[2];
    const float* v1 = (const float*)d_in[3];
    const float* b1 = (const float*)d_in[4];
    const float* w2 = (const float*)d_in[5];
    const float* m2 = (const float*)d_in[6];
    const float* v2 = (const float*)d_in[7];
    const float* b2 = (const float*)d_in[8];
    const float* w3 = (const float*)d_in[9];
    const float* m3 = (const float*)d_in[10];
    const float* v3 = (const float*)d_in[11];
    const float* b3 = (const float*)d_in[12];
    const float* w4 = (const float*)d_in[13];
    const float* m4 = (const float*)d_in[14];
    const float* v4 = (const float*)d_in[15];
    const float* b4 = (const float*)d_in[16];
    float* out = (float*)d_out;

    char* ws = (char*)d_ws;
    size_t off = 0;
    auto take = [&](size_t bytes) -> char* {
        char* p = ws + off;
        off += (bytes + 255) & ~(size_t)255;
        return p;
    };
    uint32_t* y1p = (uint32_t*)take((size_t)64 * 63 * 63 * 4);
    uint2*    y2p = (uint2*)take((size_t)64 * 31 * 31 * 8);
    uint32_t* y3p = (uint32_t*)take((size_t)64 * 15 * 15 * 16);
    float*    w1s = (float*)take(864 * 4);
    uint32_t* w2p = (uint32_t*)take(576 * 4);
    uint32_t* w3p = (uint32_t*)take(2304 * 4);
    uint32_t* w4p = (uint32_t*)take(9216 * 4);

    // weight prep: 864 + 576 + 2304 + 9216 = 12960 items
    pack_all<<<(864 + 576 + 2304 + 9216 + 255) / 256, 256, 0, stream>>>(
        w1, w2, w3, w4, w1s, w2p, w3p, w4p);

    conv1_k<<<64 * 16, 256, 0, stream>>>(x, w1s, m1, v1, b1, y1p);

    bconv2<<<(64 * 31 * 8) / 4, 256, 0, stream>>>(y1p, w2p, m2, v2, b2, y2p);

    bconv3<<<(64 * 15 * 8 * 2) / 4, 256, 0, stream>>>(y2p, w3p, m3, v3, b3, y3p);

    bconv4<<<64 * 7 * 7, 256, 0, stream>>>((const uint4*)y3p, w4p, m4, v4, b4, out);
}